// Round 12
// baseline (77.990 us; speedup 1.0000x reference)
//
#include <hip/hip_runtime.h>
#include <hip/hip_bf16.h>

#define B_  512
#define T_  256
#define C_  384
#define H_  64
#define SCALE_ 0.05103103630798287f   // 384^-0.5

typedef float f32x4  __attribute__((ext_vector_type(4)));
typedef float f32x16 __attribute__((ext_vector_type(16)));
typedef short bf16x8 __attribute__((ext_vector_type(8)));
typedef short bf16x4 __attribute__((ext_vector_type(4)));

__device__ __forceinline__ unsigned short f2bf(float f) {
    union { float f; unsigned u; } v; v.f = f;
    unsigned r = v.u + 0x7FFFu + ((v.u >> 16) & 1u);   // RNE
    return (unsigned short)(r >> 16);
}
__device__ __forceinline__ float bf2f(short s) {
    union { unsigned u; float f; } v; v.u = ((unsigned)(unsigned short)s) << 16;
    return v.f;
}
__device__ __forceinline__ unsigned cvt_pk_bf16(float lo, float hi) {
    unsigned r;
    asm("v_cvt_pk_bf16_f32 %0, %1, %2" : "=v"(r) : "v"(lo), "v"(hi));
    return r;
}
// XOR-swizzled [R][64]-short tile index (row = 128 B = 8 x 16B blocks).
__device__ __forceinline__ int swz64(int row, int col) {
    return row * 64 + (((col >> 3) ^ (row & 7)) << 3) + (col & 7);
}

// LDS (shorts): smem[68096] = 136192 B.  (layout identical to R11)
//  Phase-1: wst0 [0,12288), wst1 [12288,24576)  W^T k=64-chunk dbuf.
//  After final phase-1 barrier (aliases):
//    Ks [0,16384)            [256][64] swz64
//    Cb [16384,33792)        8 bands x [32 q][68 h] bf16 partial-O exchange
//    Cml [33792,34816)       8 bands x 32 q x {m,l} f32
//  Qs [34816,51200)          [256][64] swz64
//  Vt [51200,68096)          [64][264] (V^T rows h, cols t)
//
// ONE change vs R11: amdgpu_waves_per_eu(4,4) pins the register budget at 128
// VGPR (LDS caps us at 1 WG/CU = 4 waves/SIMD anyway; the compiler's default
// 64-VGPR squeeze was spilling every wide live set -> WRITE_SIZE inflation in
// R4/R10/R11).
__global__ __launch_bounds__(1024)
__attribute__((amdgpu_waves_per_eu(4, 4)))
void att_head_kernel(
    const float* __restrict__ x,  const float* __restrict__ Wk,
    const float* __restrict__ Wq, const float* __restrict__ Wv,
    float* __restrict__ out)
{
    __shared__ __align__(16) short smem[68096];
    short* const wst0 = smem;
    short* const wst1 = smem + 12288;
    short* const Ks   = smem;                  // alias
    short* const Cb   = smem + 16384;          // alias (dead wst1 tail)
    float* const Cml  = (float*)(smem + 33792);
    short* const Qs   = smem + 34816;
    short* const Vt   = smem + 51200;

    const int tid  = threadIdx.x;
    const int b    = blockIdx.x;
    const int w    = tid >> 6;        // 0..15
    const int lane = tid & 63;
    const int hh   = lane >> 5;       // half-wave index
    const int li   = lane & 31;
    const int wb   = w >> 1;          // row band (32 rows) == phase-2 q-band
    const int wc   = w & 1;           // col half (96 cols) == phase-2 kv-half

    const float* xb = x + (size_t)b * T_ * C_;
    const float* Wm[3] = { Wk, Wq, Wv };

    // ---- W staging: thread (w,lane): rows m*64+lane, k-quad w, swizzled b64 ----
    auto stageW = [&](int kc, short* buf) {
        #pragma unroll
        for (int m = 0; m < 3; m++) {
            const float* Wp = Wm[m] + (size_t)(kc + w * 4) * H_ + lane;
            bf16x4 pk;
            #pragma unroll
            for (int jj = 0; jj < 4; jj++) pk[jj] = (short)f2bf(Wp[jj * H_]);
            const int row = m * 64 + lane;
            const int k0  = w * 4;
            *(bf16x4*)&buf[row * 64 + (((k0 >> 3) ^ (row & 7)) << 3) + (k0 & 7)] = pk;
        }
    };

    // A rows for this wave: 32*wb + li; per-lane k-base 8*hh
    const float* xrow = xb + (size_t)(32 * wb + li) * C_ + 8 * hh;
    float4 xr[4][2];
    auto loadX = [&](int j) {
        #pragma unroll
        for (int kk = 0; kk < 4; kk++) {
            xr[kk][0] = *(const float4*)(xrow + 64 * j + 16 * kk);
            xr[kk][1] = *(const float4*)(xrow + 64 * j + 16 * kk + 4);
        }
    };

    f32x16 acc[3];
    #pragma unroll
    for (int ct = 0; ct < 3; ct++)
        #pragma unroll
        for (int r = 0; r < 16; r++) acc[ct][r] = 0.f;

    // ---------------- Phase 1: 6 chunks of k=64, 32x32x16 MFMA ----------------
    loadX(0);
    stageW(0, wst0);
    asm volatile("s_waitcnt lgkmcnt(0)\n\ts_barrier" ::: "memory");

    #pragma unroll
    for (int j = 0; j < 6; j++) {
        short* const cur = (j & 1) ? wst1 : wst0;
        short* const alt = (j & 1) ? wst0 : wst1;
        bf16x8 afs[4];
        #pragma unroll
        for (int kk = 0; kk < 4; kk++) {
            union { bf16x8 v; unsigned u[4]; } a;
            a.u[0] = cvt_pk_bf16(xr[kk][0].x, xr[kk][0].y);
            a.u[1] = cvt_pk_bf16(xr[kk][0].z, xr[kk][0].w);
            a.u[2] = cvt_pk_bf16(xr[kk][1].x, xr[kk][1].y);
            a.u[3] = cvt_pk_bf16(xr[kk][1].z, xr[kk][1].w);
            afs[kk] = a.v;
        }
        if (j < 5) { loadX(j + 1); stageW((j + 1) * 64, alt); }
        #pragma unroll
        for (int kk = 0; kk < 4; kk++) {
            #pragma unroll
            for (int ct = 0; ct < 3; ct++) {
                const int row = 96 * wc + 32 * ct + li;
                const bf16x8 bfr = *(const bf16x8*)&cur[row * 64 +
                        (((2 * kk + hh) ^ (li & 7)) << 3)];
                acc[ct] = __builtin_amdgcn_mfma_f32_32x32x16_bf16(afs[kk], bfr, acc[ct], 0, 0, 0);
            }
        }
        asm volatile("s_waitcnt lgkmcnt(0)\n\ts_barrier" ::: "memory");
    }
    // wst dead from here

    // ---- Epilogue: scatter K,Q (b16, swz64) and V (packed b64) ----
    #pragma unroll
    for (int ct = 0; ct < 3; ct++) {
        const int gc = 96 * wc + 32 * ct;     // wave-uniform
        if (gc < 64) {
            #pragma unroll
            for (int r = 0; r < 16; r++) {
                const int row = 32 * wb + (r & 3) + 8 * (r >> 2) + 4 * hh;
                Ks[swz64(row, gc + li)] = (short)f2bf(acc[ct][r]);
            }
        } else if (gc < 128) {
            #pragma unroll
            for (int r = 0; r < 16; r++) {
                const int row = 32 * wb + (r & 3) + 8 * (r >> 2) + 4 * hh;
                Qs[swz64(row, gc - 64 + li)] = (short)f2bf(acc[ct][r]);
            }
        } else {
            const int h = gc - 128 + li;
            #pragma unroll
            for (int rq = 0; rq < 4; rq++) {
                const int t0 = 32 * wb + 8 * rq + 4 * hh;
                bf16x4 pk;
                #pragma unroll
                for (int e = 0; e < 4; e++) pk[e] = (short)f2bf(acc[ct][4 * rq + e]);
                *(bf16x4*)&Vt[h * 264 + t0] = pk;
            }
        }
    }
    asm volatile("s_waitcnt lgkmcnt(0)\n\ts_barrier" ::: "memory");

    // ---------------- Phase 2: wave (qb=wb, kh=wc), 32x32 kv-tiles ----------------
    const int qb = wb, kh = wc;
    bf16x8 qf[4];
    #pragma unroll
    for (int kk = 0; kk < 4; kk++)
        qf[kk] = *(const bf16x8*)&Qs[(32 * qb + li) * 64 + (((2 * kk + hh) ^ (li & 7)) << 3)];

    const float NEG_INF = -__builtin_inff();
    float mrun = NEG_INF, lrun = 0.f;
    f32x16 accO[2];
    #pragma unroll
    for (int ha = 0; ha < 2; ha++)
        #pragma unroll
        for (int r = 0; r < 16; r++) accO[ha][r] = 0.f;

    auto doTile = [&](int nt, bool diag) {
        f32x16 sA;
        #pragma unroll
        for (int r = 0; r < 16; r++) sA[r] = 0.f;
        #pragma unroll
        for (int kk = 0; kk < 4; kk++) {
            const bf16x8 kfr = *(const bf16x8*)&Ks[(32 * nt + li) * 64 +
                    (((2 * kk + hh) ^ (li & 7)) << 3)];
            sA = __builtin_amdgcn_mfma_f32_32x32x16_bf16(kfr, qf[kk], sA, 0, 0, 0);
        }
        bf16x8 vfr[2][2];
        #pragma unroll
        for (int ha = 0; ha < 2; ha++)
            #pragma unroll
            for (int k2 = 0; k2 < 2; k2++)
                vfr[ha][k2] = *(const bf16x8*)&Vt[(32 * ha + li) * 264 +
                        32 * nt + 16 * k2 + 8 * hh];
        float mt = NEG_INF;
        #pragma unroll
        for (int r = 0; r < 16; r++) {
            float v = sA[r] * SCALE_;
            if (diag) {
                const int kv_l = (r & 3) + 8 * (r >> 2) + 4 * hh;
                v = (kv_l <= li) ? v : NEG_INF;
            }
            sA[r] = v;
            mt = fmaxf(mt, v);
        }
        mt = fmaxf(mt, __shfl_xor(mt, 32, 64));
        if (!__all(mt <= mrun + 8.0f)) {          // defer-max (THR=8)
            const float mnew = fmaxf(mrun, mt);
            const float f = __expf(mrun - mnew);
            mrun = mnew; lrun *= f;
            #pragma unroll
            for (int ha = 0; ha < 2; ha++)
                #pragma unroll
                for (int r = 0; r < 16; r++) accO[ha][r] *= f;
        }
        #pragma unroll
        for (int r = 0; r < 16; r++) {
            const float p = __expf(sA[r] - mrun);
            sA[r] = p;
            lrun += p;
        }
        // P^T -> PV B-operand in registers: 8 cvt_pk + 4 permlane32_swap
        #pragma unroll
        for (int k2 = 0; k2 < 2; k2++) {
            unsigned ua = cvt_pk_bf16(sA[8 * k2 + 0], sA[8 * k2 + 1]);
            unsigned ub = cvt_pk_bf16(sA[8 * k2 + 2], sA[8 * k2 + 3]);
            unsigned uc = cvt_pk_bf16(sA[8 * k2 + 4], sA[8 * k2 + 5]);
            unsigned ud = cvt_pk_bf16(sA[8 * k2 + 6], sA[8 * k2 + 7]);
            asm volatile("v_permlane32_swap_b32 %0, %1" : "+v"(ua), "+v"(uc));
            asm volatile("v_permlane32_swap_b32 %0, %1" : "+v"(ub), "+v"(ud));
            union { bf16x8 v; unsigned u[4]; } pf;
            pf.u[0] = ua; pf.u[1] = ub; pf.u[2] = uc; pf.u[3] = ud;
            #pragma unroll
            for (int ha = 0; ha < 2; ha++)
                accO[ha] = __builtin_amdgcn_mfma_f32_32x32x16_bf16(vfr[ha][k2], pf.v, accO[ha], 0, 0, 0);
        }
    };

    for (int nt = kh; nt < qb; nt += 2) doTile(nt, false);
    if ((qb & 1) == kh) doTile(qb, true);

    lrun += __shfl_xor(lrun, 32, 64);

    // ---- combine the two kv-halves of each q-band ----
    if (kh == 1) {
        #pragma unroll
        for (int ha = 0; ha < 2; ha++)
            #pragma unroll
            for (int rq = 0; rq < 4; rq++) {
                bf16x4 pk;
                #pragma unroll
                for (int e = 0; e < 4; e++) pk[e] = (short)f2bf(accO[ha][4 * rq + e]);
                *(bf16x4*)&Cb[qb * 2176 + li * 68 + 32 * ha + 8 * rq + 4 * hh] = pk;
            }
        if (hh == 0) {
            Cml[qb * 64 + li * 2]     = mrun;
            Cml[qb * 64 + li * 2 + 1] = lrun;
        }
    }
    asm volatile("s_waitcnt lgkmcnt(0)\n\ts_barrier" ::: "memory");

    if (kh == 0) {
        const float m1 = Cml[qb * 64 + li * 2];
        const float l1 = Cml[qb * 64 + li * 2 + 1];
        const float mn = fmaxf(mrun, m1);
        const float f0 = __expf(mrun - mn);
        const float f1 = __expf(m1 - mn);
        const float inv = 1.f / (lrun * f0 + l1 * f1);
        float* orow = out + ((size_t)b * T_ + 32 * qb + li) * H_;
        #pragma unroll
        for (int ha = 0; ha < 2; ha++)
            #pragma unroll
            for (int rq = 0; rq < 4; rq++) {
                const bf16x4 pv = *(const bf16x4*)&Cb[qb * 2176 + li * 68 +
                        32 * ha + 8 * rq + 4 * hh];
                float4 o;
                o.x = (accO[ha][4 * rq + 0] * f0 + bf2f(pv[0]) * f1) * inv;
                o.y = (accO[ha][4 * rq + 1] * f0 + bf2f(pv[1]) * f1) * inv;
                o.z = (accO[ha][4 * rq + 2] * f0 + bf2f(pv[2]) * f1) * inv;
                o.w = (accO[ha][4 * rq + 3] * f0 + bf2f(pv[3]) * f1) * inv;
                *(float4*)&orow[32 * ha + 8 * rq + 4 * hh] = o;
            }
    }
}

extern "C" void kernel_launch(void* const* d_in, const int* in_sizes, int n_in,
                              void* d_out, int out_size, void* d_ws, size_t ws_size,
                              hipStream_t stream) {
    const float* x  = (const float*)d_in[0];
    const float* Wk = (const float*)d_in[1];
    const float* Wq = (const float*)d_in[2];
    const float* Wv = (const float*)d_in[3];
    float* out = (float*)d_out;
    (void)d_ws; (void)ws_size; (void)in_sizes; (void)n_in; (void)out_size;
    att_head_kernel<<<dim3(B_), dim3(1024), 0, stream>>>(x, Wk, Wq, Wv, out);
}

// Round 13
// 75.194 us; speedup vs baseline: 1.0372x; 1.0372x over previous
//
#include <hip/hip_runtime.h>
#include <hip/hip_bf16.h>

#define B_  512
#define T_  256
#define C_  384
#define H_  64
#define SCALE_ 0.05103103630798287f   // 384^-0.5

typedef float f32x4  __attribute__((ext_vector_type(4)));
typedef float f32x16 __attribute__((ext_vector_type(16)));
typedef short bf16x8 __attribute__((ext_vector_type(8)));
typedef short bf16x4 __attribute__((ext_vector_type(4)));

__device__ __forceinline__ unsigned short f2bf(float f) {
    union { float f; unsigned u; } v; v.f = f;
    unsigned r = v.u + 0x7FFFu + ((v.u >> 16) & 1u);   // RNE
    return (unsigned short)(r >> 16);
}
__device__ __forceinline__ unsigned cvt_pk_bf16(float lo, float hi) {
    unsigned r;
    asm("v_cvt_pk_bf16_f32 %0, %1, %2" : "=v"(r) : "v"(lo), "v"(hi));
    return r;
}
// XOR-swizzled [R][64]-short tile index (row = 128 B = 8 x 16B blocks).
__device__ __forceinline__ int swz64(int row, int col) {
    return row * 64 + (((col >> 3) ^ (row & 7)) << 3) + (col & 7);
}

// LDS (shorts): smem[70144] = 140288 B.
//  Phase-1: wst0 [0,12288), wst1 [12288,24576)  W^T k=64-chunk dbuf (R9-proven).
//  After final phase-1 barrier (aliases over wst):
//    Ks [0,16384)       [256][64] swz64
//    Qs [16384,32768)   [256][64] swz64
//  Non-aliased:
//    Vt [32768,49664)   [64][264] (V^T rows h, cols t)
//    Pb [49664,70144)   16 waves x 2x[16][40] P^T dbuf scratch
//
// Phase 1: 32x32x16 MFMA (R11-proven) -> B-fragment LDS reads HALVED vs R9
// (each b128 read feeds 32K FLOP). acc[3] f32x16 lives in AGPRs; arch live set
// ~48 (xr+afs) fits the 64-arch budget. Phase 2: R9-verbatim slim 16x16 S^T
// online-softmax (sA = 2x f32x4 -> no AGPR round-trip bloat, no spill).
__global__ __launch_bounds__(1024, 4) void att_head_kernel(
    const float* __restrict__ x,  const float* __restrict__ Wk,
    const float* __restrict__ Wq, const float* __restrict__ Wv,
    float* __restrict__ out)
{
    __shared__ __align__(16) short smem[70144];
    short* const wst0 = smem;
    short* const wst1 = smem + 12288;
    short* const Ks   = smem;                  // alias (written after wst dead)
    short* const Qs   = smem + 16384;          // alias (written after wst dead)
    short* const Vt   = smem + 32768;
    short* const Pb   = smem + 49664;

    const int tid  = threadIdx.x;
    const int b    = blockIdx.x;
    const int w    = tid >> 6;        // 0..15
    const int lane = tid & 63;
    const int g    = lane >> 4;
    const int i    = lane & 15;
    const int hh   = lane >> 5;       // half-wave index (32x32 layout)
    const int li   = lane & 31;
    const int wb   = w >> 1;          // phase-1 row band (32 rows)
    const int wc   = w & 1;           // phase-1 col half (96 cols)

    const float* xb = x + (size_t)b * T_ * C_;
    const float* Wm[3] = { Wk, Wq, Wv };

    // ---- W staging (R9-proven): thread (w,lane): rows m*64+lane, k-quad w ----
    auto stageW = [&](int kc, short* buf) {
        #pragma unroll
        for (int m = 0; m < 3; m++) {
            const float* Wp = Wm[m] + (size_t)(kc + w * 4) * H_ + lane;
            bf16x4 pk;
            #pragma unroll
            for (int jj = 0; jj < 4; jj++) pk[jj] = (short)f2bf(Wp[jj * H_]);
            const int row = m * 64 + lane;
            const int k0  = w * 4;
            *(bf16x4*)&buf[row * 64 + (((k0 >> 3) ^ (row & 7)) << 3) + (k0 & 7)] = pk;
        }
    };

    // A rows for this wave: 32*wb + li; per-lane k-base 8*hh
    const float* xrow = xb + (size_t)(32 * wb + li) * C_ + 8 * hh;
    float4 xr[4][2];
    auto loadX = [&](int j) {
        #pragma unroll
        for (int kk = 0; kk < 4; kk++) {
            xr[kk][0] = *(const float4*)(xrow + 64 * j + 16 * kk);
            xr[kk][1] = *(const float4*)(xrow + 64 * j + 16 * kk + 4);
        }
    };

    f32x16 acc[3];
    #pragma unroll
    for (int ct = 0; ct < 3; ct++)
        #pragma unroll
        for (int r = 0; r < 16; r++) acc[ct][r] = 0.f;

    // ---------------- Phase 1: 6 chunks of k=64, 32x32x16 MFMA (R11) ----------
    loadX(0);
    stageW(0, wst0);
    asm volatile("s_waitcnt lgkmcnt(0)\n\ts_barrier" ::: "memory");

    #pragma unroll
    for (int j = 0; j < 6; j++) {
        short* const cur = (j & 1) ? wst1 : wst0;
        short* const alt = (j & 1) ? wst0 : wst1;
        bf16x8 afs[4];
        #pragma unroll
        for (int kk = 0; kk < 4; kk++) {
            union { bf16x8 v; unsigned u[4]; } a;
            a.u[0] = cvt_pk_bf16(xr[kk][0].x, xr[kk][0].y);
            a.u[1] = cvt_pk_bf16(xr[kk][0].z, xr[kk][0].w);
            a.u[2] = cvt_pk_bf16(xr[kk][1].x, xr[kk][1].y);
            a.u[3] = cvt_pk_bf16(xr[kk][1].z, xr[kk][1].w);
            afs[kk] = a.v;
        }
        if (j < 5) { loadX(j + 1); stageW((j + 1) * 64, alt); }
        #pragma unroll
        for (int kk = 0; kk < 4; kk++) {
            #pragma unroll
            for (int ct = 0; ct < 3; ct++) {
                const int row = 96 * wc + 32 * ct + li;
                const bf16x8 bfr = *(const bf16x8*)&cur[row * 64 +
                        (((2 * kk + hh) ^ (li & 7)) << 3)];
                acc[ct] = __builtin_amdgcn_mfma_f32_32x32x16_bf16(afs[kk], bfr, acc[ct], 0, 0, 0);
            }
        }
        asm volatile("s_waitcnt lgkmcnt(0)\n\ts_barrier" ::: "memory");
    }
    // wst dead from here

    // ---- Epilogue (R11-proven): scatter K,Q (b16, swz64) and V (packed b64) ----
    #pragma unroll
    for (int ct = 0; ct < 3; ct++) {
        const int gc = 96 * wc + 32 * ct;     // wave-uniform
        if (gc < 64) {
            #pragma unroll
            for (int r = 0; r < 16; r++) {
                const int row = 32 * wb + (r & 3) + 8 * (r >> 2) + 4 * hh;
                Ks[swz64(row, gc + li)] = (short)f2bf(acc[ct][r]);
            }
        } else if (gc < 128) {
            #pragma unroll
            for (int r = 0; r < 16; r++) {
                const int row = 32 * wb + (r & 3) + 8 * (r >> 2) + 4 * hh;
                Qs[swz64(row, gc - 64 + li)] = (short)f2bf(acc[ct][r]);
            }
        } else {
            const int h = gc - 128 + li;
            #pragma unroll
            for (int rq = 0; rq < 4; rq++) {
                const int t0 = 32 * wb + 8 * rq + 4 * hh;
                bf16x4 pk;
                #pragma unroll
                for (int e = 0; e < 4; e++) pk[e] = (short)f2bf(acc[ct][4 * rq + e]);
                *(bf16x4*)&Vt[h * 264 + t0] = pk;
            }
        }
    }
    asm volatile("s_waitcnt lgkmcnt(0)\n\ts_barrier" ::: "memory");

    // ---------------- Phase 2 (R9-verbatim): online causal attention, S^T --------
    const int rb = 16 * w;
    bf16x8 qf[2];
    #pragma unroll
    for (int ks = 0; ks < 2; ks++)
        qf[ks] = *(const bf16x8*)&Qs[(rb + i) * 64 + (((4 * ks + g) ^ (i & 7)) << 3)];

    short* const myP = Pb + w * 1280;    // two [16][40] buffers
    const float NEG_INF = -__builtin_inff();
    float mrun = NEG_INF, lrun = 0.f;
    f32x4 accO[4];
    #pragma unroll
    for (int ht = 0; ht < 4; ht++) accO[ht] = f32x4{0.f, 0.f, 0.f, 0.f};

    auto PVADD = [&](int bufsel, int ck) {
        const bf16x8 pf = *(const bf16x8*)&myP[bufsel * 640 + i * 40 + 8 * g];
        #pragma unroll
        for (int ht = 0; ht < 4; ht++) {
            const bf16x8 vf = *(const bf16x8*)&Vt[(16 * ht + i) * 264 + 32 * ck + 8 * g];
            accO[ht] = __builtin_amdgcn_mfma_f32_16x16x32_bf16(vf, pf, accO[ht], 0, 0, 0);
        }
    };

    const int npair = w >> 1;
    #pragma unroll
    for (int p = 0; p < 8; p++) {
        if (p <= npair) {                // wave-uniform
            f32x4 sA[2];
            sA[0] = f32x4{0.f, 0.f, 0.f, 0.f};
            sA[1] = f32x4{0.f, 0.f, 0.f, 0.f};
            #pragma unroll
            for (int s = 0; s < 2; s++) {
                const int nt = 2 * p + s;
                if (nt <= w) {           // wave-uniform
                    #pragma unroll
                    for (int ks = 0; ks < 2; ks++) {
                        const bf16x8 kfr = *(const bf16x8*)&Ks[(16 * nt + i) * 64 +
                                (((4 * ks + g) ^ (i & 7)) << 3)];
                        sA[s] = __builtin_amdgcn_mfma_f32_16x16x32_bf16(kfr, qf[ks], sA[s], 0, 0, 0);
                    }
                }
            }
            if (p > 0) PVADD((p - 1) & 1, p - 1);   // pipelined PV of prev pair

            float mt = NEG_INF;
            #pragma unroll
            for (int s = 0; s < 2; s++)
                #pragma unroll
                for (int r = 0; r < 4; r++) {
                    const int kv = 16 * (2 * p + s) + 4 * g + r;
                    const bool ok = (2 * p + s <= w) && (kv <= rb + i);
                    const float v = ok ? sA[s][r] * SCALE_ : NEG_INF;
                    sA[s][r] = v;
                    mt = fmaxf(mt, v);
                }
            mt = fmaxf(mt, __shfl_xor(mt, 16, 64));
            mt = fmaxf(mt, __shfl_xor(mt, 32, 64));

            if (!__all(mt <= mrun + 8.0f)) {        // defer-max (THR=8)
                const float mnew = fmaxf(mrun, mt);
                const float f = __expf(mrun - mnew);
                mrun = mnew; lrun *= f;
                #pragma unroll
                for (int ht = 0; ht < 4; ht++)
                    #pragma unroll
                    for (int r = 0; r < 4; r++) accO[ht][r] *= f;
            }
            #pragma unroll
            for (int s = 0; s < 2; s++) {
                const float p0 = __expf(sA[s][0] - mrun);
                const float p1 = __expf(sA[s][1] - mrun);
                const float p2 = __expf(sA[s][2] - mrun);
                const float p3 = __expf(sA[s][3] - mrun);
                lrun += (p0 + p1) + (p2 + p3);
                union { bf16x4 v; unsigned u[2]; } pk;
                pk.u[0] = cvt_pk_bf16(p0, p1);
                pk.u[1] = cvt_pk_bf16(p2, p3);
                *(bf16x4*)&myP[(p & 1) * 640 + i * 40 + 16 * s + 4 * g] = pk.v;
            }
        }
    }
    PVADD(npair & 1, npair);             // drain last pair

    lrun += __shfl_xor(lrun, 16, 64);
    lrun += __shfl_xor(lrun, 32, 64);
    const float inv = 1.f / lrun;

    float* orow = out + ((size_t)b * T_ + rb + i) * H_;
    #pragma unroll
    for (int ht = 0; ht < 4; ht++) {
        float4 o;
        o.x = accO[ht][0] * inv;
        o.y = accO[ht][1] * inv;
        o.z = accO[ht][2] * inv;
        o.w = accO[ht][3] * inv;
        *(float4*)&orow[16 * ht + 4 * g] = o;
    }
}

extern "C" void kernel_launch(void* const* d_in, const int* in_sizes, int n_in,
                              void* d_out, int out_size, void* d_ws, size_t ws_size,
                              hipStream_t stream) {
    const float* x  = (const float*)d_in[0];
    const float* Wk = (const float*)d_in[1];
    const float* Wq = (const float*)d_in[2];
    const float* Wv = (const float*)d_in[3];
    float* out = (float*)d_out;
    (void)d_ws; (void)ws_size; (void)in_sizes; (void)n_in; (void)out_size;
    att_head_kernel<<<dim3(B_), dim3(1024), 0, stream>>>(x, Wk, Wq, Wv, out);
}